// Round 1
// baseline (41287.863 us; speedup 1.0000x reference)
//
#include <hip/hip_runtime.h>
#include <math.h>

// ---------------------------------------------------------------------------
// AWD-LSTM: 3-layer LSTM (400->1152->1152->400) over T=128,B=64 + decoder to
// 33278 tokens. Strategy:
//   per layer:  pre = X_seq @ W_ih^T + b_ih + b_hh        (one big GEMM)
//               for t: gates = pre[t] + h_{t-1} @ W_hh^T  (fused step kernel)
//   decoder:    out = H2_seq @ W_dec^T + b_dec
// All fp32. h is double-buffered via the sequence buffer (read t-1, write t).
// ---------------------------------------------------------------------------

// C[M,N] = A[M,K] @ W[N,K]^T + b1[n] (+ b2[n] if non-null)
// Block: 16x16 threads, 64x64 output tile, 4x4 microtile, K-step 16.
// M, K must be multiples of 64/16 (true for all call sites); N is guarded.
__global__ __launch_bounds__(256) void gemm_bias_kernel(
    const float* __restrict__ A, const float* __restrict__ W,
    const float* __restrict__ b1, const float* __restrict__ b2,
    float* __restrict__ C, int M, int N, int K)
{
    __shared__ float As[16][65];  // [k][m], padded
    __shared__ float Ws[16][65];  // [k][n], padded
    const int tx = threadIdx.x, ty = threadIdx.y;
    const int tid = ty * 16 + tx;
    const int m0 = blockIdx.y * 64;
    const int n0 = blockIdx.x * 64;

    float acc[4][4] = {};

    for (int k0 = 0; k0 < K; k0 += 16) {
#pragma unroll
        for (int i = 0; i < 4; ++i) {
            int idx = tid + i * 256;
            int r = idx >> 4;      // 0..63
            int kk = idx & 15;     // 0..15
            As[kk][r] = A[(size_t)(m0 + r) * K + (k0 + kk)];
            int ng = n0 + r;
            Ws[kk][r] = (ng < N) ? W[(size_t)ng * K + (k0 + kk)] : 0.f;
        }
        __syncthreads();
#pragma unroll
        for (int kk = 0; kk < 16; ++kk) {
            float a[4], w[4];
#pragma unroll
            for (int mm = 0; mm < 4; ++mm) a[mm] = As[kk][ty * 4 + mm];
#pragma unroll
            for (int nn = 0; nn < 4; ++nn) w[nn] = Ws[kk][tx * 4 + nn];
#pragma unroll
            for (int mm = 0; mm < 4; ++mm)
#pragma unroll
                for (int nn = 0; nn < 4; ++nn)
                    acc[mm][nn] += a[mm] * w[nn];
        }
        __syncthreads();
    }

#pragma unroll
    for (int nn = 0; nn < 4; ++nn) {
        int n = n0 + tx * 4 + nn;
        if (n >= N) continue;
        float bias = b1[n] + (b2 ? b2[n] : 0.f);
#pragma unroll
        for (int mm = 0; mm < 4; ++mm) {
            int m = m0 + ty * 4 + mm;
            C[(size_t)m * N + n] = acc[mm][nn] + bias;
        }
    }
}

// One LSTM timestep. Each block: 16 j-values (blockIdx.x*16) x 4 gates x 64
// batches. acc[mm][g] accumulates h_{t-1} @ W_hh^T; pre (incl. both biases)
// is added at the end; nonlinearities + cell update fused.
// Tile column c (0..63): gate = c&3, jj = c>>2  (thread tx owns j0+tx, all 4 gates)
__global__ __launch_bounds__(256) void lstm_step_kernel(
    const float* __restrict__ pre_t,  // (64, 4*dout) for this t
    const float* __restrict__ Whh,    // (4*dout, dout) row-major, i|f|g|o blocks
    const float* __restrict__ h_in,   // (64, dout)  = h_{t-1}
    float* __restrict__ c_state,      // (64, dout)  in/out (thread-private RMW)
    float* __restrict__ h_out,        // (64, dout)  = h_t
    int dout)
{
    __shared__ float Hs[16][65];  // [k][batch]
    __shared__ float Ws[16][65];  // [k][tile col]
    const int tx = threadIdx.x, ty = threadIdx.y;
    const int tid = ty * 16 + tx;
    const int j0 = blockIdx.x * 16;

    float acc[4][4] = {};  // [batch mm][gate]

    for (int k0 = 0; k0 < dout; k0 += 16) {
#pragma unroll
        for (int i = 0; i < 4; ++i) {
            int idx = tid + i * 256;
            int r = idx >> 4;
            int kk = idx & 15;
            Hs[kk][r] = h_in[(size_t)r * dout + (k0 + kk)];
            int gate = r & 3;
            int jj = r >> 2;
            Ws[kk][r] = Whh[(size_t)(gate * dout + j0 + jj) * dout + (k0 + kk)];
        }
        __syncthreads();
#pragma unroll
        for (int kk = 0; kk < 16; ++kk) {
            float a[4], w[4];
#pragma unroll
            for (int mm = 0; mm < 4; ++mm) a[mm] = Hs[kk][ty * 4 + mm];
#pragma unroll
            for (int g = 0; g < 4; ++g) w[g] = Ws[kk][tx * 4 + g];
#pragma unroll
            for (int mm = 0; mm < 4; ++mm)
#pragma unroll
                for (int g = 0; g < 4; ++g)
                    acc[mm][g] += a[mm] * w[g];
        }
        __syncthreads();
    }

    const int j = j0 + tx;
#pragma unroll
    for (int mm = 0; mm < 4; ++mm) {
        int b = ty * 4 + mm;
        const size_t pb = (size_t)b * 4 * dout;
        float gi = acc[mm][0] + pre_t[pb + 0 * (size_t)dout + j];
        float gf = acc[mm][1] + pre_t[pb + 1 * (size_t)dout + j];
        float gg = acc[mm][2] + pre_t[pb + 2 * (size_t)dout + j];
        float go = acc[mm][3] + pre_t[pb + 3 * (size_t)dout + j];
        float si = 1.f / (1.f + expf(-gi));
        float sf = 1.f / (1.f + expf(-gf));
        float so = 1.f / (1.f + expf(-go));
        float tg = tanhf(gg);
        size_t sidx = (size_t)b * dout + j;
        float cn = sf * c_state[sidx] + si * tg;
        float hn = so * tanhf(cn);
        c_state[sidx] = cn;
        h_out[sidx] = hn;
    }
}

extern "C" void kernel_launch(void* const* d_in, const int* in_sizes, int n_in,
                              void* d_out, int out_size, void* d_ws, size_t ws_size,
                              hipStream_t stream)
{
    const int T = 128, B = 64, EMB = 400, HID = 1152, NTOK = 33278;
    const int TB = T * B;  // 8192

    const float* x     = (const float*)d_in[0];
    const float* h0[3] = {(const float*)d_in[1], (const float*)d_in[2], (const float*)d_in[3]};
    const float* c0[3] = {(const float*)d_in[4], (const float*)d_in[5], (const float*)d_in[6]};
    const float* W_ih[3] = {(const float*)d_in[7],  (const float*)d_in[11], (const float*)d_in[15]};
    const float* W_hh[3] = {(const float*)d_in[8],  (const float*)d_in[12], (const float*)d_in[16]};
    const float* b_ih[3] = {(const float*)d_in[9],  (const float*)d_in[13], (const float*)d_in[17]};
    const float* b_hh[3] = {(const float*)d_in[10], (const float*)d_in[14], (const float*)d_in[18]};
    const float* W_dec = (const float*)d_in[19];
    const float* b_dec = (const float*)d_in[20];
    float* out = (float*)d_out;

    // workspace layout (~240.3 MB)
    char* ws = (char*)d_ws;
    size_t off = 0;
    float* pre   = (float*)(ws + off); off += (size_t)TB * 4 * HID * sizeof(float); // 151 MB
    float* seq_a = (float*)(ws + off); off += (size_t)TB * HID * sizeof(float);     // 37.7 MB
    float* seq_b = (float*)(ws + off); off += (size_t)TB * HID * sizeof(float);     // 37.7 MB
    float* seq_c = (float*)(ws + off); off += (size_t)TB * EMB * sizeof(float);     // 13.1 MB
    float* cst[3];
    cst[0] = (float*)(ws + off); off += (size_t)B * HID * sizeof(float);
    cst[1] = (float*)(ws + off); off += (size_t)B * HID * sizeof(float);
    cst[2] = (float*)(ws + off); off += (size_t)B * EMB * sizeof(float);

    const int din[3] = {EMB, HID, HID};
    const int dh[3]  = {HID, HID, EMB};
    const float* lin[3] = {x, seq_a, seq_b};
    float* lout[3] = {seq_a, seq_b, seq_c};

    dim3 blk(16, 16);

    for (int l = 0; l < 3; ++l) {
        const int N4 = 4 * dh[l];
        hipMemcpyAsync(cst[l], c0[l], (size_t)B * dh[l] * sizeof(float),
                       hipMemcpyDeviceToDevice, stream);
        // pre = X_seq @ W_ih^T + b_ih + b_hh
        gemm_bias_kernel<<<dim3(N4 / 64, TB / 64), blk, 0, stream>>>(
            lin[l], W_ih[l], b_ih[l], b_hh[l], pre, TB, N4, din[l]);
        for (int t = 0; t < T; ++t) {
            const float* h_in = (t == 0) ? h0[l]
                                         : (lout[l] + (size_t)(t - 1) * B * dh[l]);
            lstm_step_kernel<<<dim3(dh[l] / 16), blk, 0, stream>>>(
                pre + (size_t)t * B * N4, W_hh[l], h_in, cst[l],
                lout[l] + (size_t)t * B * dh[l], dh[l]);
        }
    }

    // decoder: out = H2_seq @ W_dec^T + b_dec
    gemm_bias_kernel<<<dim3((NTOK + 63) / 64, TB / 64), blk, 0, stream>>>(
        seq_c, W_dec, b_dec, nullptr, out, TB, NTOK, EMB);
}

// Round 2
// 25000.377 us; speedup vs baseline: 1.6515x; 1.6515x over previous
//
#include <hip/hip_runtime.h>
#include <math.h>

typedef unsigned short u16;
typedef __attribute__((ext_vector_type(8))) short short8;
typedef __attribute__((ext_vector_type(4))) float f32x4;

__device__ __forceinline__ u16 f32_to_bf16(float x) {
    union { float f; unsigned int u; } v; v.f = x;
    unsigned int u = v.u;
    return (u16)((u + 0x7FFFu + ((u >> 16) & 1u)) >> 16);
}
__device__ __forceinline__ float bf16_to_f32(u16 h) {
    union { unsigned int u; float f; } v; v.u = ((unsigned int)h) << 16; return v.f;
}

// ---------------------------------------------------------------------------
// split fp32 [N][K] (optionally gate-permuted rows) -> bf16 hi/lo [Npad][Kpad]
// perm=1: source row for dst row n is (n&3)*(N/4) + (n>>2)   (c = j*4+g)
// pads are zero-filled.
// ---------------------------------------------------------------------------
__global__ void split_pad_kernel(const float* __restrict__ src,
                                 u16* __restrict__ hi, u16* __restrict__ lo,
                                 int N, int K, int Npad, int Kpad, int perm)
{
    int idx = blockIdx.x * 256 + threadIdx.x;
    if (idx >= Npad * Kpad) return;
    int n = idx / Kpad, k = idx - n * Kpad;
    float x = 0.f;
    if (n < N && k < K) {
        int srow = n;
        if (perm) { int dout = N >> 2; srow = (n & 3) * dout + (n >> 2); }
        x = src[(size_t)srow * K + k];
    }
    u16 h = f32_to_bf16(x);
    hi[idx] = h;
    lo[idx] = f32_to_bf16(x - bf16_to_f32(h));
}

// bsum[c] = b_ih[orig(c)] + b_hh[orig(c)] in permuted gate space
__global__ void bias_perm_kernel(const float* __restrict__ bi,
                                 const float* __restrict__ bh,
                                 float* __restrict__ out, int N4)
{
    int c = blockIdx.x * 256 + threadIdx.x;
    if (c >= N4) return;
    int dout = N4 >> 2;
    int s = (c & 3) * dout + (c >> 2);
    out[c] = bi[s] + bh[s];
}

// ---------------------------------------------------------------------------
// C[M][ldc] = A @ W^T + bias, bf16x3 MFMA.
// A: amode 0 -> Af32 [M][Kreal] fp32 (split on the fly, k-guarded)
//    amode 1 -> Ahi/Alo [M][Kp] bf16 (pads pre-zeroed)
// W: always pre-split hi/lo [Npad][Kp], pads zeroed (no guards needed).
// Block 256 thr = 4 waves; tile 128x128; wave tile 64x64 (4x4 frags 16x16x32).
// ---------------------------------------------------------------------------
__global__ __launch_bounds__(256) void gemm3m(
    const float* __restrict__ Af32,
    const u16* __restrict__ Ahi, const u16* __restrict__ Alo,
    const u16* __restrict__ Whi, const u16* __restrict__ Wlo,
    const float* __restrict__ bias,
    float* __restrict__ C,
    int M, int Nreal, int Kreal, int Kp, int ldc, int amode)
{
    __shared__ __align__(16) u16 As[2][128][32];
    __shared__ __align__(16) u16 Ws[2][128][32];

    const int tid  = threadIdx.x;
    const int lane = tid & 63, wave = tid >> 6;
    const int m0 = blockIdx.y * 128, n0 = blockIdx.x * 128;
    const int wm = (wave >> 1) * 64, wn = (wave & 1) * 64;

    f32x4 acc[4][4];
#pragma unroll
    for (int i = 0; i < 4; ++i)
#pragma unroll
        for (int j = 0; j < 4; ++j)
#pragma unroll
            for (int r = 0; r < 4; ++r) acc[i][j][r] = 0.f;

    const int srow = tid >> 2;       // 0..63
    const int sq   = tid & 3;        // chunk 0..3 (8 shorts each)
    const int fr   = lane & 15;
    const int fq   = lane >> 4;
    const int rcol = ((fq ^ (fr & 3)) * 8);   // swizzled read column (ushorts)

    for (int k0 = 0; k0 < Kp; k0 += 32) {
#pragma unroll
        for (int half = 0; half < 2; ++half) {
            int row = half * 64 + srow;
            int kc  = k0 + sq * 8;
            int dq  = (sq ^ (row & 3)) * 8;
            // ---- A ----
            if (amode == 0) {
                union { u16 s[8]; short8 v; } uh, ul;
                if (kc + 8 <= Kreal) {
                    const float* p = &Af32[(size_t)(m0 + row) * Kreal + kc];
#pragma unroll
                    for (int j = 0; j < 8; ++j) {
                        float xv = p[j];
                        u16 hh = f32_to_bf16(xv);
                        uh.s[j] = hh;
                        ul.s[j] = f32_to_bf16(xv - bf16_to_f32(hh));
                    }
                } else {
#pragma unroll
                    for (int j = 0; j < 8; ++j) { uh.s[j] = 0; ul.s[j] = 0; }
                }
                *(short8*)&As[0][row][dq] = uh.v;
                *(short8*)&As[1][row][dq] = ul.v;
            } else {
                size_t ao = (size_t)(m0 + row) * Kp + kc;
                *(short8*)&As[0][row][dq] = *(const short8*)(Ahi + ao);
                *(short8*)&As[1][row][dq] = *(const short8*)(Alo + ao);
            }
            // ---- W ----
            {
                size_t wo = (size_t)(n0 + row) * Kp + kc;
                *(short8*)&Ws[0][row][dq] = *(const short8*)(Whi + wo);
                *(short8*)&Ws[1][row][dq] = *(const short8*)(Wlo + wo);
            }
        }
        __syncthreads();

        short8 ah[4], al[4], wh[4], wl[4];
#pragma unroll
        for (int f = 0; f < 4; ++f) {
            int arow = wm + f * 16 + fr;
            ah[f] = *(const short8*)&As[0][arow][rcol];
            al[f] = *(const short8*)&As[1][arow][rcol];
            int wrow = wn + f * 16 + fr;
            wh[f] = *(const short8*)&Ws[0][wrow][rcol];
            wl[f] = *(const short8*)&Ws[1][wrow][rcol];
        }
#pragma unroll
        for (int i = 0; i < 4; ++i)
#pragma unroll
            for (int j = 0; j < 4; ++j) {
                acc[i][j] = __builtin_amdgcn_mfma_f32_16x16x32_bf16(ah[i], wh[j], acc[i][j], 0, 0, 0);
                acc[i][j] = __builtin_amdgcn_mfma_f32_16x16x32_bf16(ah[i], wl[j], acc[i][j], 0, 0, 0);
                acc[i][j] = __builtin_amdgcn_mfma_f32_16x16x32_bf16(al[i], wh[j], acc[i][j], 0, 0, 0);
            }
        __syncthreads();
    }

#pragma unroll
    for (int j = 0; j < 4; ++j) {
        int n = n0 + wn + j * 16 + fr;
        if (n >= Nreal) continue;
        float bv = bias ? bias[n] : 0.f;
#pragma unroll
        for (int i = 0; i < 4; ++i) {
            int mrow = m0 + wm + i * 16 + fq * 4;
#pragma unroll
            for (int r = 0; r < 4; ++r)
                C[(size_t)(mrow + r) * ldc + n] = acc[i][j][r] + bv;
        }
    }
}

// ---------------------------------------------------------------------------
// LSTM step, bf16x3 MFMA, G^T = W_perm @ h^T (so each thread's f32x4 = the
// 4 gates i,f,g,o of one (j,b)). Direct global fragment loads, ping-ponged.
// Block 256 thr = 4 waves; block covers 256 c-cols x 64 batches.
// ---------------------------------------------------------------------------
#define STEP_LOAD(WH, WL, HH, HL, K0)                                     \
    _Pragma("unroll")                                                     \
    for (int f = 0; f < 4; ++f) {                                         \
        size_t wo = (size_t)(c0 + f * 16 + fr) * Kp + (K0) + fq * 8;      \
        WH[f] = *(const short8*)(Whi + wo);                               \
        WL[f] = *(const short8*)(Wlo + wo);                               \
        size_t ho = (size_t)(f * 16 + fr) * Kp + (K0) + fq * 8;           \
        HH[f] = *(const short8*)(hhi + ho);                               \
        HL[f] = *(const short8*)(hlo + ho);                               \
    }

#define STEP_MFMA(WH, WL, HH, HL)                                         \
    _Pragma("unroll")                                                     \
    for (int i = 0; i < 4; ++i) {                                         \
        _Pragma("unroll")                                                 \
        for (int j = 0; j < 4; ++j) {                                     \
            acc[i][j] = __builtin_amdgcn_mfma_f32_16x16x32_bf16(WH[i], HH[j], acc[i][j], 0, 0, 0); \
            acc[i][j] = __builtin_amdgcn_mfma_f32_16x16x32_bf16(WH[i], HL[j], acc[i][j], 0, 0, 0); \
            acc[i][j] = __builtin_amdgcn_mfma_f32_16x16x32_bf16(WL[i], HH[j], acc[i][j], 0, 0, 0); \
        }                                                                 \
    }

__global__ __launch_bounds__(256) void lstm_step3m(
    const u16* __restrict__ Whi, const u16* __restrict__ Wlo,  // [N4p256][Kp]
    const u16* __restrict__ hhi, const u16* __restrict__ hlo,  // [64][Kp]
    const float* __restrict__ pre_t,                           // [64][N4real]
    float* __restrict__ cst,                                   // [64][dout]
    u16* __restrict__ ohi, u16* __restrict__ olo,              // [64][Kp]
    int N4real, int Kp, int dout)
{
    const int tid  = threadIdx.x;
    const int lane = tid & 63, wave = tid >> 6;
    const int c0 = blockIdx.x * 256 + wave * 64;
    const int fr = lane & 15, fq = lane >> 4;

    f32x4 acc[4][4];
#pragma unroll
    for (int i = 0; i < 4; ++i)
#pragma unroll
        for (int j = 0; j < 4; ++j)
#pragma unroll
            for (int r = 0; r < 4; ++r) acc[i][j][r] = 0.f;

    short8 w0h[4], w0l[4], p0h[4], p0l[4];
    short8 w1h[4], w1l[4], p1h[4], p1l[4];

    STEP_LOAD(w0h, w0l, p0h, p0l, 0);
    int k0 = 0;
    for (;;) {
        int kn = k0 + 32;
        if (kn < Kp) STEP_LOAD(w1h, w1l, p1h, p1l, kn);
        STEP_MFMA(w0h, w0l, p0h, p0l);
        if (kn >= Kp) break;
        k0 = kn + 32;
        if (k0 < Kp) STEP_LOAD(w0h, w0l, p0h, p0l, k0);
        STEP_MFMA(w1h, w1l, p1h, p1l);
        if (k0 >= Kp) break;
    }

#pragma unroll
    for (int i = 0; i < 4; ++i) {
        int cbase = c0 + i * 16 + fq * 4;     // multiple of 4: gates 0..3
        if (cbase >= N4real) continue;
        int j = cbase >> 2;
#pragma unroll
        for (int fb = 0; fb < 4; ++fb) {
            int b = fb * 16 + fr;
            const float* pp = &pre_t[(size_t)b * N4real + cbase];
            float gi = acc[i][fb][0] + pp[0];
            float gf = acc[i][fb][1] + pp[1];
            float gg = acc[i][fb][2] + pp[2];
            float go = acc[i][fb][3] + pp[3];
            float si = 1.f / (1.f + expf(-gi));
            float sf = 1.f / (1.f + expf(-gf));
            float so = 1.f / (1.f + expf(-go));
            float tg = tanhf(gg);
            size_t ci = (size_t)b * dout + j;
            float cn = sf * cst[ci] + si * tg;
            float hv = so * tanhf(cn);
            cst[ci] = cn;
            u16 hh = f32_to_bf16(hv);
            ohi[(size_t)b * Kp + j] = hh;
            olo[(size_t)b * Kp + j] = f32_to_bf16(hv - bf16_to_f32(hh));
        }
    }
}

// ---------------------------------------------------------------------------
extern "C" void kernel_launch(void* const* d_in, const int* in_sizes, int n_in,
                              void* d_out, int out_size, void* d_ws, size_t ws_size,
                              hipStream_t stream)
{
    const int T = 128, B = 64, EMB = 400, HID = 1152, NTOK = 33278;
    const int TB = T * B;

    const float* x     = (const float*)d_in[0];
    const float* h0[3] = {(const float*)d_in[1], (const float*)d_in[2], (const float*)d_in[3]};
    const float* c0[3] = {(const float*)d_in[4], (const float*)d_in[5], (const float*)d_in[6]};
    const float* W_ih[3] = {(const float*)d_in[7],  (const float*)d_in[11], (const float*)d_in[15]};
    const float* W_hh[3] = {(const float*)d_in[8],  (const float*)d_in[12], (const float*)d_in[16]};
    const float* b_ih[3] = {(const float*)d_in[9],  (const float*)d_in[13], (const float*)d_in[17]};
    const float* b_hh[3] = {(const float*)d_in[10], (const float*)d_in[14], (const float*)d_in[18]};
    const float* W_dec = (const float*)d_in[19];
    const float* b_dec = (const float*)d_in[20];

    const int din[3]    = {EMB, HID, HID};    // input dim per layer
    const int Kpre[3]   = {416, 1152, 1152};  // padded K of pre-GEMM
    const int dh[3]     = {HID, HID, EMB};    // hidden dim per layer
    const int Kph[3]    = {1152, 1152, 416};  // padded h storage width
    const int N4[3]     = {4608, 4608, 1600};
    const int N4p128[3] = {4608, 4608, 1664};
    const int N4p256[3] = {4608, 4608, 1792};

    char* wsp = (char*)d_ws;
    size_t off = 0;
    auto alloc = [&](size_t bytes) -> char* {
        char* p = wsp + off; off = (off + bytes + 255) & ~(size_t)255; return p;
    };

    float* preQ = (float*)alloc((size_t)2048 * 4608 * 4);   // quarter pre buffer
    u16 *seqHi[3], *seqLo[3];
    for (int l = 0; l < 3; ++l) {
        seqHi[l] = (u16*)alloc((size_t)TB * Kph[l] * 2);
        seqLo[l] = (u16*)alloc((size_t)TB * Kph[l] * 2);
    }
    u16 *WhhHi[3], *WhhLo[3];
    for (int l = 0; l < 3; ++l) {
        WhhHi[l] = (u16*)alloc((size_t)N4p256[l] * Kph[l] * 2);
        WhhLo[l] = (u16*)alloc((size_t)N4p256[l] * Kph[l] * 2);
    }
    u16* WbufHi = (u16*)alloc((size_t)33280 * 416 * 2);  // max(W_ih*, W_dec) split
    u16* WbufLo = (u16*)alloc((size_t)33280 * 416 * 2);
    float* bsum[3];
    for (int l = 0; l < 3; ++l) bsum[l] = (float*)alloc(4608 * 4);
    float* cst[3];
    for (int l = 0; l < 3; ++l) cst[l] = (float*)alloc((size_t)B * dh[l] * 4);
    u16 *h0Hi[3], *h0Lo[3];
    for (int l = 0; l < 3; ++l) {
        h0Hi[l] = (u16*)alloc((size_t)B * Kph[l] * 2);
        h0Lo[l] = (u16*)alloc((size_t)B * Kph[l] * 2);
    }

    // zero seqC (layer 2 h storage has padded columns 400..415)
    hipMemsetAsync(seqHi[2], 0, (size_t)TB * Kph[2] * 2, stream);
    hipMemsetAsync(seqLo[2], 0, (size_t)TB * Kph[2] * 2, stream);

    auto run_split = [&](const float* src, u16* hi, u16* lo,
                         int N, int K, int Npad, int Kpad, int perm) {
        int total = Npad * Kpad;
        split_pad_kernel<<<(total + 255) / 256, 256, 0, stream>>>(
            src, hi, lo, N, K, Npad, Kpad, perm);
    };

    for (int l = 0; l < 3; ++l) {
        hipMemcpyAsync(cst[l], c0[l], (size_t)B * dh[l] * 4,
                       hipMemcpyDeviceToDevice, stream);
        run_split(h0[l], h0Hi[l], h0Lo[l], B, dh[l], B, Kph[l], 0);
        run_split(W_hh[l], WhhHi[l], WhhLo[l], N4[l], dh[l], N4p256[l], Kph[l], 1);
        bias_perm_kernel<<<(N4[l] + 255) / 256, 256, 0, stream>>>(
            b_ih[l], b_hh[l], bsum[l], N4[l]);
        run_split(W_ih[l], WbufHi, WbufLo, N4[l], din[l], N4p128[l], Kpre[l], 1);

        for (int q = 0; q < 4; ++q) {
            const float* Aq = (l == 0) ? (x + (size_t)q * 2048 * EMB) : nullptr;
            const u16* Ah = (l == 0) ? nullptr : (seqHi[l-1] + (size_t)q * 2048 * Kph[l-1]);
            const u16* Al = (l == 0) ? nullptr : (seqLo[l-1] + (size_t)q * 2048 * Kph[l-1]);
            gemm3m<<<dim3(N4p128[l] / 128, 16), 256, 0, stream>>>(
                Aq, Ah, Al, WbufHi, WbufLo, bsum[l], preQ,
                2048, N4[l], din[l], Kpre[l], N4[l], (l == 0) ? 0 : 1);

            for (int tl = 0; tl < 32; ++tl) {
                int t = q * 32 + tl;
                const u16* hih = (t == 0) ? h0Hi[l] : (seqHi[l] + (size_t)(t - 1) * B * Kph[l]);
                const u16* hil = (t == 0) ? h0Lo[l] : (seqLo[l] + (size_t)(t - 1) * B * Kph[l]);
                lstm_step3m<<<dim3(N4p256[l] / 256), 256, 0, stream>>>(
                    WhhHi[l], WhhLo[l], hih, hil,
                    preQ + (size_t)tl * B * N4[l],
                    cst[l],
                    seqHi[l] + (size_t)t * B * Kph[l],
                    seqLo[l] + (size_t)t * B * Kph[l],
                    N4[l], Kph[l], dh[l]);
            }
        }
    }

    // decoder: out = H2 @ W_dec^T + b_dec
    run_split(W_dec, WbufHi, WbufLo, NTOK, EMB, 33280, 416, 0);
    gemm3m<<<dim3(260, 64), 256, 0, stream>>>(
        nullptr, seqHi[2], seqLo[2], WbufHi, WbufLo, b_dec, (float*)d_out,
        TB, NTOK, EMB, 416, NTOK, 1);
}

// Round 3
// 8835.588 us; speedup vs baseline: 4.6729x; 2.8295x over previous
//
#include <hip/hip_runtime.h>
#include <math.h>

typedef unsigned short u16;
typedef __attribute__((ext_vector_type(8))) short short8;
typedef __attribute__((ext_vector_type(4))) float f32x4;

__device__ __forceinline__ u16 f32_to_bf16(float x) {
    union { float f; unsigned int u; } v; v.f = x;
    unsigned int u = v.u;
    return (u16)((u + 0x7FFFu + ((u >> 16) & 1u)) >> 16);
}
__device__ __forceinline__ float bf16_to_f32(u16 h) {
    union { unsigned int u; float f; } v; v.u = ((unsigned int)h) << 16; return v.f;
}

// ---------------------------------------------------------------------------
// split fp32 [N][K] (optionally gate-permuted rows) -> bf16 hi/lo [Npad][Kpad]
// perm=1: source row for dst row n is (n&3)*(N/4) + (n>>2)   (c = j*4+g)
// ---------------------------------------------------------------------------
__global__ void split_pad_kernel(const float* __restrict__ src,
                                 u16* __restrict__ hi, u16* __restrict__ lo,
                                 int N, int K, int Npad, int Kpad, int perm)
{
    int idx = blockIdx.x * 256 + threadIdx.x;
    if (idx >= Npad * Kpad) return;
    int n = idx / Kpad, k = idx - n * Kpad;
    float x = 0.f;
    if (n < N && k < K) {
        int srow = n;
        if (perm) { int dout = N >> 2; srow = (n & 3) * dout + (n >> 2); }
        x = src[(size_t)srow * K + k];
    }
    u16 h = f32_to_bf16(x);
    hi[idx] = h;
    lo[idx] = f32_to_bf16(x - bf16_to_f32(h));
}

__global__ void bias_perm_kernel(const float* __restrict__ bi,
                                 const float* __restrict__ bh,
                                 float* __restrict__ out, int N4)
{
    int c = blockIdx.x * 256 + threadIdx.x;
    if (c >= N4) return;
    int dout = N4 >> 2;
    int s = (c & 3) * dout + (c >> 2);
    out[c] = bi[s] + bh[s];
}

// ---------------------------------------------------------------------------
// C[M][ldc] = A @ W^T + bias, bf16x3 MFMA. M = grid.y*128 (exact).
// amode 0: Af32 [M][lda] fp32, split on the fly (k >= Kreal -> 0)
// amode 1: Ahi/Alo [M][lda] bf16 (pads beyond Kp never read; k-loop < Kp)
// W: pre-split hi/lo [Npad][Kp], pads zeroed.
// LDS chunk swizzle q' = q ^ ((row>>2)&3)  -> 2-way conflicts (free).
// ---------------------------------------------------------------------------
__global__ __launch_bounds__(256) void gemm3m(
    const float* __restrict__ Af32,
    const u16* __restrict__ Ahi, const u16* __restrict__ Alo,
    const u16* __restrict__ Whi, const u16* __restrict__ Wlo,
    const float* __restrict__ bias,
    float* __restrict__ C,
    int Nreal, int Kreal, int Kp, int lda, int ldc, int amode)
{
    __shared__ __align__(16) u16 As[2][128][32];
    __shared__ __align__(16) u16 Ws[2][128][32];

    const int tid  = threadIdx.x;
    const int lane = tid & 63, wave = tid >> 6;
    const int m0 = blockIdx.y * 128, n0 = blockIdx.x * 128;
    const int wm = (wave >> 1) * 64, wn = (wave & 1) * 64;

    f32x4 acc[4][4];
#pragma unroll
    for (int i = 0; i < 4; ++i)
#pragma unroll
        for (int j = 0; j < 4; ++j)
#pragma unroll
            for (int r = 0; r < 4; ++r) acc[i][j][r] = 0.f;

    const int srow = tid >> 2;
    const int sq   = tid & 3;
    const int dq   = (sq ^ ((srow >> 2) & 3)) * 8;
    const int fr   = lane & 15;
    const int fq   = lane >> 4;
    const int rcol = (fq ^ ((fr >> 2) & 3)) * 8;

    for (int k0 = 0; k0 < Kp; k0 += 32) {
#pragma unroll
        for (int half = 0; half < 2; ++half) {
            int row = half * 64 + srow;
            int kc  = k0 + sq * 8;
            if (amode == 0) {
                union { u16 s[8]; short8 v; } uh, ul;
                if (kc + 8 <= Kreal) {
                    const float* p = &Af32[(size_t)(m0 + row) * lda + kc];
#pragma unroll
                    for (int j = 0; j < 8; ++j) {
                        float xv = p[j];
                        u16 hh = f32_to_bf16(xv);
                        uh.s[j] = hh;
                        ul.s[j] = f32_to_bf16(xv - bf16_to_f32(hh));
                    }
                } else {
#pragma unroll
                    for (int j = 0; j < 8; ++j) { uh.s[j] = 0; ul.s[j] = 0; }
                }
                *(short8*)&As[0][row][dq] = uh.v;
                *(short8*)&As[1][row][dq] = ul.v;
            } else {
                size_t ao = (size_t)(m0 + row) * lda + kc;
                *(short8*)&As[0][row][dq] = *(const short8*)(Ahi + ao);
                *(short8*)&As[1][row][dq] = *(const short8*)(Alo + ao);
            }
            size_t wo = (size_t)(n0 + row) * Kp + kc;
            *(short8*)&Ws[0][row][dq] = *(const short8*)(Whi + wo);
            *(short8*)&Ws[1][row][dq] = *(const short8*)(Wlo + wo);
        }
        __syncthreads();

        short8 ah[4], al[4], wh[4], wl[4];
#pragma unroll
        for (int f = 0; f < 4; ++f) {
            int arow = wm + f * 16 + fr;
            ah[f] = *(const short8*)&As[0][arow][rcol];
            al[f] = *(const short8*)&As[1][arow][rcol];
            int wrow = wn + f * 16 + fr;
            wh[f] = *(const short8*)&Ws[0][wrow][rcol];
            wl[f] = *(const short8*)&Ws[1][wrow][rcol];
        }
#pragma unroll
        for (int i = 0; i < 4; ++i)
#pragma unroll
            for (int j = 0; j < 4; ++j) {
                acc[i][j] = __builtin_amdgcn_mfma_f32_16x16x32_bf16(ah[i], wh[j], acc[i][j], 0, 0, 0);
                acc[i][j] = __builtin_amdgcn_mfma_f32_16x16x32_bf16(ah[i], wl[j], acc[i][j], 0, 0, 0);
                acc[i][j] = __builtin_amdgcn_mfma_f32_16x16x32_bf16(al[i], wh[j], acc[i][j], 0, 0, 0);
            }
        __syncthreads();
    }

#pragma unroll
    for (int j = 0; j < 4; ++j) {
        int n = n0 + wn + j * 16 + fr;
        if (n >= Nreal) continue;
        float bv = bias ? bias[n] : 0.f;
#pragma unroll
        for (int i = 0; i < 4; ++i) {
            int mrow = m0 + wm + i * 16 + fq * 4;
#pragma unroll
            for (int r = 0; r < 4; ++r)
                C[(size_t)(mrow + r) * ldc + n] = acc[i][j][r] + bv;
        }
    }
}

// ---------------------------------------------------------------------------
// Persistent LSTM: one launch = 64 timesteps of one layer. W_hh slice (32
// gate-cols x Kp, hi+lo) lives in dynamic LDS (swizzled q^=(row&7), 2-way).
// Block b-coverage: wave = b-quarter (16 b), each wave does both 16-col tiles.
// Grid-wide spin barrier (device-scope atomics) between steps; all blocks
// co-resident (1 block/CU via LDS, grid <= 256). c-state in registers.
// ---------------------------------------------------------------------------
#define PF(S, KT_) do {                                                        \
    int q_ = (((KT_) * 4 + fq) ^ sxor) * 8;                                    \
    a0h_##S = *(const short8*)&Wlds[rA * Kp + q_];                             \
    a0l_##S = *(const short8*)&Wlds[(32 + rA) * Kp + q_];                      \
    a1h_##S = *(const short8*)&Wlds[rB * Kp + q_];                             \
    a1l_##S = *(const short8*)&Wlds[(32 + rB) * Kp + q_];                      \
    hh_##S = *(const short8*)(hrow_hi + (KT_) * 32 + fq * 8);                  \
    hl_##S = *(const short8*)(hrow_lo + (KT_) * 32 + fq * 8);                  \
} while (0)

#define CM(S) do {                                                             \
    accA = __builtin_amdgcn_mfma_f32_16x16x32_bf16(a0h_##S, hh_##S, accA, 0, 0, 0); \
    accB = __builtin_amdgcn_mfma_f32_16x16x32_bf16(a1h_##S, hh_##S, accB, 0, 0, 0); \
    accA = __builtin_amdgcn_mfma_f32_16x16x32_bf16(a0h_##S, hl_##S, accA, 0, 0, 0); \
    accB = __builtin_amdgcn_mfma_f32_16x16x32_bf16(a1h_##S, hl_##S, accB, 0, 0, 0); \
    accA = __builtin_amdgcn_mfma_f32_16x16x32_bf16(a0l_##S, hh_##S, accA, 0, 0, 0); \
    accB = __builtin_amdgcn_mfma_f32_16x16x32_bf16(a1l_##S, hh_##S, accB, 0, 0, 0); \
} while (0)

__global__ __launch_bounds__(256, 1) void persistent_lstm(
    const u16* __restrict__ Whi, const u16* __restrict__ Wlo,   // [N4][Kp]
    const u16* __restrict__ h0hi, const u16* __restrict__ h0lo, // [64][Kp]
    u16* __restrict__ seqHi, u16* __restrict__ seqLo,           // [T*64][Kp]
    const float* __restrict__ pre,                              // [64*64][N4]
    const float* __restrict__ c_in, float* __restrict__ c_out,  // [64][dout]
    int* __restrict__ cnt,                                      // [64]
    int t0, int N4, int Kp, int dout, int G)
{
    extern __shared__ __align__(16) u16 Wlds[];   // [2][32][Kp] swizzled
    const int tid  = threadIdx.x;
    const int lane = tid & 63, wave = tid >> 6;
    const int fr = lane & 15, fq = lane >> 4;
    const int c0blk = blockIdx.x * 32;
    const int CH = Kp >> 3;
    const int b = wave * 16 + fr;

    // stage W slice into LDS, chunk slot = q ^ (row&7)
    for (int idx = tid; idx < 64 * CH; idx += 256) {
        int buf = idx / (32 * CH);
        int rem = idx - buf * 32 * CH;
        int r = rem / CH, q = rem - r * CH;
        const u16* src = buf ? Wlo : Whi;
        short8 v = *(const short8*)(src + (size_t)(c0blk + r) * Kp + q * 8);
        *(short8*)&Wlds[(buf * 32 + r) * Kp + (q ^ (r & 7)) * 8] = v;
    }

    const int cA = c0blk + fq * 4;
    const int cB = cA + 16;
    const int jA = cA >> 2, jB = cB >> 2;
    float cregA = c_in[(size_t)b * dout + jA];
    float cregB = c_in[(size_t)b * dout + jB];

    const int rA = fr, rB = 16 + fr;
    const int sxor = fr & 7;           // (rA&7) == (rB&7)
    const int KT = Kp >> 5;            // multiple of 4 by construction
    __syncthreads();

    for (int ts = 0; ts < 64; ++ts) {
        const int t = t0 + ts;
        const u16* hbase_hi = (t == 0) ? h0hi : seqHi + (size_t)(t - 1) * 64 * Kp;
        const u16* hbase_lo = (t == 0) ? h0lo : seqLo + (size_t)(t - 1) * 64 * Kp;
        const u16* hrow_hi = hbase_hi + (size_t)b * Kp;
        const u16* hrow_lo = hbase_lo + (size_t)b * Kp;

        f32x4 accA = {0.f, 0.f, 0.f, 0.f};
        f32x4 accB = {0.f, 0.f, 0.f, 0.f};
        short8 a0h_0, a0l_0, a1h_0, a1l_0, hh_0, hl_0;
        short8 a0h_1, a0l_1, a1h_1, a1l_1, hh_1, hl_1;
        short8 a0h_2, a0l_2, a1h_2, a1l_2, hh_2, hl_2;
        short8 a0h_3, a0l_3, a1h_3, a1l_3, hh_3, hl_3;

        PF(0, 0); PF(1, 1); PF(2, 2); PF(3, 3);
        for (int kt = 0; kt < KT - 4; kt += 4) {
            CM(0); PF(0, kt + 4);
            CM(1); PF(1, kt + 5);
            CM(2); PF(2, kt + 6);
            CM(3); PF(3, kt + 7);
        }
        CM(0); CM(1); CM(2); CM(3);

        // epilogue: gates -> c,h ; write h (hi/lo)
#pragma unroll
        for (int ct = 0; ct < 2; ++ct) {
            f32x4 a = ct ? accB : accA;
            int cc = ct ? cB : cA;
            int j  = ct ? jB : jA;
            const float* pp = pre + (size_t)(ts * 64 + b) * N4 + cc;
            float gi = a[0] + pp[0];
            float gf = a[1] + pp[1];
            float gg = a[2] + pp[2];
            float go = a[3] + pp[3];
            float si = 1.f / (1.f + expf(-gi));
            float sf = 1.f / (1.f + expf(-gf));
            float so = 1.f / (1.f + expf(-go));
            float tg = tanhf(gg);
            float cn = sf * (ct ? cregB : cregA) + si * tg;
            float hv = so * tanhf(cn);
            if (ct) cregB = cn; else cregA = cn;
            u16 hb = f32_to_bf16(hv);
            size_t so_ = (size_t)(t * 64 + b) * Kp + j;
            seqHi[so_] = hb;
            seqLo[so_] = f32_to_bf16(hv - bf16_to_f32(hb));
        }

        // grid-wide barrier (skip after last step)
        if (ts != 63) {
            __syncthreads();
            if (tid == 0) {
                __threadfence();
                __hip_atomic_fetch_add(cnt + ts, 1, __ATOMIC_RELEASE, __HIP_MEMORY_SCOPE_AGENT);
                while (__hip_atomic_load(cnt + ts, __ATOMIC_ACQUIRE, __HIP_MEMORY_SCOPE_AGENT) < G)
                    __builtin_amdgcn_s_sleep(2);
                __threadfence();
            }
            __syncthreads();
        }
    }

    c_out[(size_t)b * dout + jA] = cregA;
    c_out[(size_t)b * dout + jB] = cregB;
}

// ---------------------------------------------------------------------------
extern "C" void kernel_launch(void* const* d_in, const int* in_sizes, int n_in,
                              void* d_out, int out_size, void* d_ws, size_t ws_size,
                              hipStream_t stream)
{
    const int T = 128, B = 64, EMB = 400, HID = 1152, NTOK = 33278;
    const int TB = T * B;

    const float* x     = (const float*)d_in[0];
    const float* h0[3] = {(const float*)d_in[1], (const float*)d_in[2], (const float*)d_in[3]};
    const float* c0[3] = {(const float*)d_in[4], (const float*)d_in[5], (const float*)d_in[6]};
    const float* W_ih[3] = {(const float*)d_in[7],  (const float*)d_in[11], (const float*)d_in[15]};
    const float* W_hh[3] = {(const float*)d_in[8],  (const float*)d_in[12], (const float*)d_in[16]};
    const float* b_ih[3] = {(const float*)d_in[9],  (const float*)d_in[13], (const float*)d_in[17]};
    const float* b_hh[3] = {(const float*)d_in[10], (const float*)d_in[14], (const float*)d_in[18]};
    const float* W_dec = (const float*)d_in[19];
    const float* b_dec = (const float*)d_in[20];

    const int din[3]    = {EMB, HID, HID};     // input dim per layer
    const int Kpre[3]   = {416, 1152, 1152};   // padded K of pre-GEMM
    const int dh[3]     = {HID, HID, EMB};     // hidden dim per layer
    const int KpH[3]    = {1152, 1152, 512};   // padded h width (KT%4==0)
    const int N4[3]     = {4608, 4608, 1600};
    const int N4p128[3] = {4608, 4608, 1664};
    const int Gp[3]     = {144, 144, 50};      // persistent grid (N4/32)

    char* wsp = (char*)d_ws;
    size_t off = 0;
    auto alloc = [&](size_t bytes) -> char* {
        char* p = wsp + off; off = (off + bytes + 255) & ~(size_t)255; return p;
    };

    float* pre   = (float*)alloc((size_t)4096 * 4608 * 4);        // 75.5 MB (half T)
    u16* seqHi   = (u16*)alloc((size_t)TB * 1152 * 2);            // 18.9 MB
    u16* seqLo   = (u16*)alloc((size_t)TB * 1152 * 2);            // 18.9 MB
    u16* WihHi   = (u16*)alloc((size_t)4608 * 1152 * 2);          // 10.6 MB
    u16* WihLo   = (u16*)alloc((size_t)4608 * 1152 * 2);
    u16* WhhHi   = (u16*)alloc((size_t)4608 * 1152 * 2);
    u16* WhhLo   = (u16*)alloc((size_t)4608 * 1152 * 2);
    u16* h0Hi    = (u16*)alloc((size_t)B * 1152 * 2);
    u16* h0Lo    = (u16*)alloc((size_t)B * 1152 * 2);
    float* bsum  = (float*)alloc(4608 * 4);
    float* cstb  = (float*)alloc((size_t)B * HID * 4);
    int* cnt     = (int*)alloc(6 * 64 * 4);
    // decoder W split aliases pre (pre dead by then): 2 x 27.7 MB <= 75.5 MB
    u16* WdecHi  = (u16*)pre;
    u16* WdecLo  = (u16*)pre + (size_t)33280 * 416;

    hipMemsetAsync(cnt, 0, 6 * 64 * 4, stream);
    hipFuncSetAttribute(reinterpret_cast<const void*>(persistent_lstm),
                        hipFuncAttributeMaxDynamicSharedMemorySize, 160 * 1024);

    auto run_split = [&](const float* src, u16* hi, u16* lo,
                         int N, int K, int Npad, int Kpad, int perm) {
        int total = Npad * Kpad;
        split_pad_kernel<<<(total + 255) / 256, 256, 0, stream>>>(
            src, hi, lo, N, K, Npad, Kpad, perm);
    };

    for (int l = 0; l < 3; ++l) {
        run_split(W_hh[l], WhhHi, WhhLo, N4[l], dh[l], N4[l], KpH[l], 1);
        run_split(h0[l], h0Hi, h0Lo, B, dh[l], B, KpH[l], 0);
        run_split(W_ih[l], WihHi, WihLo, N4[l], din[l], N4p128[l], Kpre[l], 1);
        bias_perm_kernel<<<(N4[l] + 255) / 256, 256, 0, stream>>>(
            b_ih[l], b_hh[l], bsum, N4[l]);

        const int ldaA = (l == 0) ? EMB : KpH[l - 1];
        const size_t ldsB = (size_t)128 * KpH[l];   // 2*32*Kp*2 bytes

        for (int halfT = 0; halfT < 2; ++halfT) {
            const float* Af32 = (l == 0) ? (x + (size_t)halfT * 4096 * EMB) : nullptr;
            const u16* Ah = (l == 0) ? nullptr : (seqHi + (size_t)halfT * 4096 * ldaA);
            const u16* Al = (l == 0) ? nullptr : (seqLo + (size_t)halfT * 4096 * ldaA);
            gemm3m<<<dim3(N4p128[l] / 128, 32), 256, 0, stream>>>(
                Af32, Ah, Al, WihHi, WihLo, bsum, pre,
                N4[l], din[l], Kpre[l], ldaA, N4[l], (l == 0) ? 0 : 1);

            const float* cin = (halfT == 0) ? c0[l] : cstb;
            persistent_lstm<<<dim3(Gp[l]), 256, ldsB, stream>>>(
                WhhHi, WhhLo, h0Hi, h0Lo, seqHi, seqLo, pre,
                cin, cstb, cnt + (l * 2 + halfT) * 64,
                halfT * 64, N4[l], KpH[l], dh[l], Gp[l]);
        }
    }

    // decoder: out = H2 @ W_dec^T + b_dec   (A stride 512, K extent 416)
    run_split(W_dec, WdecHi, WdecLo, NTOK, EMB, 33280, 416, 0);
    gemm3m<<<dim3(260, 64), 256, 0, stream>>>(
        nullptr, seqHi, seqLo, WdecHi, WdecLo, b_dec, (float*)d_out,
        NTOK, EMB, 416, 512, NTOK, 1);
}

// Round 4
// 6748.035 us; speedup vs baseline: 6.1185x; 1.3094x over previous
//
#include <hip/hip_runtime.h>
#include <math.h>

typedef unsigned short u16;
typedef __attribute__((ext_vector_type(8))) short short8;
typedef __attribute__((ext_vector_type(4))) float f32x4;

__device__ __forceinline__ u16 f32_to_bf16(float x) {
    union { float f; unsigned int u; } v; v.f = x;
    unsigned int u = v.u;
    return (u16)((u + 0x7FFFu + ((u >> 16) & 1u)) >> 16);
}
__device__ __forceinline__ float bf16_to_f32(u16 h) {
    union { unsigned int u; float f; } v; v.u = ((unsigned int)h) << 16; return v.f;
}

// ---------------------------------------------------------------------------
// split fp32 [N][K] (optionally gate-permuted rows) -> bf16 hi/lo [Npad][Kpad]
// perm=1: source row for dst row n is (n&3)*(N/4) + (n>>2)   (c = j*4+g)
// ---------------------------------------------------------------------------
__global__ void split_pad_kernel(const float* __restrict__ src,
                                 u16* __restrict__ hi, u16* __restrict__ lo,
                                 int N, int K, int Npad, int Kpad, int perm)
{
    int idx = blockIdx.x * 256 + threadIdx.x;
    if (idx >= Npad * Kpad) return;
    int n = idx / Kpad, k = idx - n * Kpad;
    float x = 0.f;
    if (n < N && k < K) {
        int srow = n;
        if (perm) { int dout = N >> 2; srow = (n & 3) * dout + (n >> 2); }
        x = src[(size_t)srow * K + k];
    }
    u16 h = f32_to_bf16(x);
    hi[idx] = h;
    lo[idx] = f32_to_bf16(x - bf16_to_f32(h));
}

__global__ void bias_perm_kernel(const float* __restrict__ bi,
                                 const float* __restrict__ bh,
                                 float* __restrict__ out, int N4)
{
    int c = blockIdx.x * 256 + threadIdx.x;
    if (c >= N4) return;
    int dout = N4 >> 2;
    int s = (c & 3) * dout + (c >> 2);
    out[c] = bi[s] + bh[s];
}

// ---------------------------------------------------------------------------
// C[M][ldc] = A @ W^T + bias, bf16x3 MFMA. M = grid.y*128 (exact).
// ---------------------------------------------------------------------------
__global__ __launch_bounds__(256) void gemm3m(
    const float* __restrict__ Af32,
    const u16* __restrict__ Ahi, const u16* __restrict__ Alo,
    const u16* __restrict__ Whi, const u16* __restrict__ Wlo,
    const float* __restrict__ bias,
    float* __restrict__ C,
    int Nreal, int Kreal, int Kp, int lda, int ldc, int amode)
{
    __shared__ __align__(16) u16 As[2][128][32];
    __shared__ __align__(16) u16 Ws[2][128][32];

    const int tid  = threadIdx.x;
    const int lane = tid & 63, wave = tid >> 6;
    const int m0 = blockIdx.y * 128, n0 = blockIdx.x * 128;
    const int wm = (wave >> 1) * 64, wn = (wave & 1) * 64;

    f32x4 acc[4][4];
#pragma unroll
    for (int i = 0; i < 4; ++i)
#pragma unroll
        for (int j = 0; j < 4; ++j)
#pragma unroll
            for (int r = 0; r < 4; ++r) acc[i][j][r] = 0.f;

    const int srow = tid >> 2;
    const int sq   = tid & 3;
    const int dq   = (sq ^ ((srow >> 2) & 3)) * 8;
    const int fr   = lane & 15;
    const int fq   = lane >> 4;
    const int rcol = (fq ^ ((fr >> 2) & 3)) * 8;

    for (int k0 = 0; k0 < Kp; k0 += 32) {
#pragma unroll
        for (int half = 0; half < 2; ++half) {
            int row = half * 64 + srow;
            int kc  = k0 + sq * 8;
            if (amode == 0) {
                union { u16 s[8]; short8 v; } uh, ul;
                if (kc + 8 <= Kreal) {
                    const float* p = &Af32[(size_t)(m0 + row) * lda + kc];
#pragma unroll
                    for (int j = 0; j < 8; ++j) {
                        float xv = p[j];
                        u16 hh = f32_to_bf16(xv);
                        uh.s[j] = hh;
                        ul.s[j] = f32_to_bf16(xv - bf16_to_f32(hh));
                    }
                } else {
#pragma unroll
                    for (int j = 0; j < 8; ++j) { uh.s[j] = 0; ul.s[j] = 0; }
                }
                *(short8*)&As[0][row][dq] = uh.v;
                *(short8*)&As[1][row][dq] = ul.v;
            } else {
                size_t ao = (size_t)(m0 + row) * lda + kc;
                *(short8*)&As[0][row][dq] = *(const short8*)(Ahi + ao);
                *(short8*)&As[1][row][dq] = *(const short8*)(Alo + ao);
            }
            size_t wo = (size_t)(n0 + row) * Kp + kc;
            *(short8*)&Ws[0][row][dq] = *(const short8*)(Whi + wo);
            *(short8*)&Ws[1][row][dq] = *(const short8*)(Wlo + wo);
        }
        __syncthreads();

        short8 ah[4], al[4], wh[4], wl[4];
#pragma unroll
        for (int f = 0; f < 4; ++f) {
            int arow = wm + f * 16 + fr;
            ah[f] = *(const short8*)&As[0][arow][rcol];
            al[f] = *(const short8*)&As[1][arow][rcol];
            int wrow = wn + f * 16 + fr;
            wh[f] = *(const short8*)&Ws[0][wrow][rcol];
            wl[f] = *(const short8*)&Ws[1][wrow][rcol];
        }
#pragma unroll
        for (int i = 0; i < 4; ++i)
#pragma unroll
            for (int j = 0; j < 4; ++j) {
                acc[i][j] = __builtin_amdgcn_mfma_f32_16x16x32_bf16(ah[i], wh[j], acc[i][j], 0, 0, 0);
                acc[i][j] = __builtin_amdgcn_mfma_f32_16x16x32_bf16(ah[i], wl[j], acc[i][j], 0, 0, 0);
                acc[i][j] = __builtin_amdgcn_mfma_f32_16x16x32_bf16(al[i], wh[j], acc[i][j], 0, 0, 0);
            }
        __syncthreads();
    }

#pragma unroll
    for (int j = 0; j < 4; ++j) {
        int n = n0 + wn + j * 16 + fr;
        if (n >= Nreal) continue;
        float bv = bias ? bias[n] : 0.f;
#pragma unroll
        for (int i = 0; i < 4; ++i) {
            int mrow = m0 + wm + i * 16 + fq * 4;
#pragma unroll
            for (int r = 0; r < 4; ++r)
                C[(size_t)(mrow + r) * ldc + n] = acc[i][j][r] + bv;
        }
    }
}

// ---------------------------------------------------------------------------
// Persistent LSTM, 64 timesteps per launch. W slice (32 gate-cols, hi+lo) in
// LDS. Depth-6 pipelined k-loop (KT % 6 == 0). Tree barrier: 8 groups
// (blockIdx&7 ~ XCD) -> root -> go flag; relaxed polls, single release
// (wbl2) before arrival, single acquire (inv) after flag.
// ---------------------------------------------------------------------------
#define PF(S, KT_) do {                                                        \
    int q_ = (((KT_) * 4 + fq) ^ sxor) * 8;                                    \
    a0h_##S = *(const short8*)&Wlds[rA * Kp + q_];                             \
    a0l_##S = *(const short8*)&Wlds[(32 + rA) * Kp + q_];                      \
    a1h_##S = *(const short8*)&Wlds[rB * Kp + q_];                             \
    a1l_##S = *(const short8*)&Wlds[(32 + rB) * Kp + q_];                      \
    hh_##S = *(const short8*)(hrow_hi + (KT_) * 32 + fq * 8);                  \
    hl_##S = *(const short8*)(hrow_lo + (KT_) * 32 + fq * 8);                  \
} while (0)

#define CM(S) do {                                                             \
    accA = __builtin_amdgcn_mfma_f32_16x16x32_bf16(a0h_##S, hh_##S, accA, 0, 0, 0); \
    accB = __builtin_amdgcn_mfma_f32_16x16x32_bf16(a1h_##S, hh_##S, accB, 0, 0, 0); \
    accA = __builtin_amdgcn_mfma_f32_16x16x32_bf16(a0h_##S, hl_##S, accA, 0, 0, 0); \
    accB = __builtin_amdgcn_mfma_f32_16x16x32_bf16(a1h_##S, hl_##S, accB, 0, 0, 0); \
    accA = __builtin_amdgcn_mfma_f32_16x16x32_bf16(a0l_##S, hh_##S, accA, 0, 0, 0); \
    accB = __builtin_amdgcn_mfma_f32_16x16x32_bf16(a1l_##S, hh_##S, accB, 0, 0, 0); \
} while (0)

__global__ __launch_bounds__(256, 1) void persistent_lstm(
    const u16* __restrict__ Whi, const u16* __restrict__ Wlo,   // [N4][Kp]
    const u16* __restrict__ h0hi, const u16* __restrict__ h0lo, // [64][Kp]
    u16* __restrict__ seqHi, u16* __restrict__ seqLo,           // [T*64][Kp]
    const float* __restrict__ pre,                              // [64*64][N4]
    const float* __restrict__ c_in, float* __restrict__ c_out,  // [64][dout]
    int* __restrict__ gcnt,   // [64][8] stride-32 padded group counters
    int* __restrict__ rootc,  // [64] stride-32 padded root counters
    int* __restrict__ go,     // [64] go flags
    int t0, int N4, int Kp, int dout, int G)
{
    extern __shared__ __align__(16) u16 Wlds[];   // [2][32][Kp] swizzled
    const int tid  = threadIdx.x;
    const int lane = tid & 63, wave = tid >> 6;
    const int fr = lane & 15, fq = lane >> 4;
    const int c0blk = blockIdx.x * 32;
    const int CH = Kp >> 3;
    const int b = wave * 16 + fr;
    const int grp = blockIdx.x & 7;
    const int gsz = (G - grp + 7) >> 3;

    // stage W slice into LDS, chunk slot = q ^ (row&7)
    for (int idx = tid; idx < 64 * CH; idx += 256) {
        int buf = idx / (32 * CH);
        int rem = idx - buf * 32 * CH;
        int r = rem / CH, q = rem - r * CH;
        const u16* src = buf ? Wlo : Whi;
        short8 v = *(const short8*)(src + (size_t)(c0blk + r) * Kp + q * 8);
        *(short8*)&Wlds[(buf * 32 + r) * Kp + (q ^ (r & 7)) * 8] = v;
    }

    const int cA = c0blk + fq * 4;
    const int cB = cA + 16;
    const int jA = cA >> 2, jB = cB >> 2;
    float cregA = c_in[(size_t)b * dout + jA];
    float cregB = c_in[(size_t)b * dout + jB];

    const int rA = fr, rB = 16 + fr;
    const int sxor = fr & 7;
    const int KT = Kp >> 5;            // multiple of 6 by construction
    __syncthreads();

    for (int ts = 0; ts < 64; ++ts) {
        const int t = t0 + ts;
        const u16* hbase_hi = (t == 0) ? h0hi : seqHi + (size_t)(t - 1) * 64 * Kp;
        const u16* hbase_lo = (t == 0) ? h0lo : seqLo + (size_t)(t - 1) * 64 * Kp;
        const u16* hrow_hi = hbase_hi + (size_t)b * Kp;
        const u16* hrow_lo = hbase_lo + (size_t)b * Kp;

        // early pre load (read-only; hides post-invalidate latency)
        const float* prow = pre + (size_t)(ts * 64 + b) * N4;
        f32x4 preA = *(const f32x4*)(prow + cA);
        f32x4 preB = *(const f32x4*)(prow + cB);

        f32x4 accA = {0.f, 0.f, 0.f, 0.f};
        f32x4 accB = {0.f, 0.f, 0.f, 0.f};
        short8 a0h_0, a0l_0, a1h_0, a1l_0, hh_0, hl_0;
        short8 a0h_1, a0l_1, a1h_1, a1l_1, hh_1, hl_1;
        short8 a0h_2, a0l_2, a1h_2, a1l_2, hh_2, hl_2;
        short8 a0h_3, a0l_3, a1h_3, a1l_3, hh_3, hl_3;
        short8 a0h_4, a0l_4, a1h_4, a1l_4, hh_4, hl_4;
        short8 a0h_5, a0l_5, a1h_5, a1l_5, hh_5, hl_5;

        PF(0, 0); PF(1, 1); PF(2, 2); PF(3, 3); PF(4, 4); PF(5, 5);
        for (int kt = 0; kt < KT - 6; kt += 6) {
            CM(0); PF(0, kt + 6);
            CM(1); PF(1, kt + 7);
            CM(2); PF(2, kt + 8);
            CM(3); PF(3, kt + 9);
            CM(4); PF(4, kt + 10);
            CM(5); PF(5, kt + 11);
        }
        CM(0); CM(1); CM(2); CM(3); CM(4); CM(5);

        // epilogue: gates -> c,h ; write h (hi/lo)
#pragma unroll
        for (int ct = 0; ct < 2; ++ct) {
            f32x4 a = ct ? accB : accA;
            f32x4 p = ct ? preB : preA;
            int j  = ct ? jB : jA;
            float gi = a[0] + p[0];
            float gf = a[1] + p[1];
            float gg = a[2] + p[2];
            float go_ = a[3] + p[3];
            float si = 1.f / (1.f + expf(-gi));
            float sf = 1.f / (1.f + expf(-gf));
            float so = 1.f / (1.f + expf(-go_));
            float tg = tanhf(gg);
            float cn = sf * (ct ? cregB : cregA) + si * tg;
            float hv = so * tanhf(cn);
            if (ct) cregB = cn; else cregA = cn;
            u16 hb = f32_to_bf16(hv);
            size_t so_ = (size_t)(t * 64 + b) * Kp + j;
            seqHi[so_] = hb;
            seqLo[so_] = f32_to_bf16(hv - bf16_to_f32(hb));
        }

        if (ts != 63) {
            __syncthreads();   // drains all waves' stores to L2 (vmcnt0 before barrier)
            if (tid == 0) {
                __builtin_amdgcn_fence(__ATOMIC_RELEASE, "agent");   // wbl2
                int old = __hip_atomic_fetch_add(&gcnt[(ts * 8 + grp) * 32], 1,
                                                 __ATOMIC_RELAXED, __HIP_MEMORY_SCOPE_AGENT);
                if (old == gsz - 1) {
                    int r = __hip_atomic_fetch_add(&rootc[ts * 32], 1,
                                                   __ATOMIC_RELAXED, __HIP_MEMORY_SCOPE_AGENT);
                    if (r == 7)
                        __hip_atomic_store(&go[ts], 1,
                                           __ATOMIC_RELAXED, __HIP_MEMORY_SCOPE_AGENT);
                }
                while (__hip_atomic_load(&go[ts], __ATOMIC_RELAXED,
                                         __HIP_MEMORY_SCOPE_AGENT) == 0)
                    __builtin_amdgcn_s_sleep(2);
                __builtin_amdgcn_fence(__ATOMIC_ACQUIRE, "agent");   // inv
            }
            __syncthreads();
        }
    }

    c_out[(size_t)b * dout + jA] = cregA;
    c_out[(size_t)b * dout + jB] = cregB;
}

// ---------------------------------------------------------------------------
extern "C" void kernel_launch(void* const* d_in, const int* in_sizes, int n_in,
                              void* d_out, int out_size, void* d_ws, size_t ws_size,
                              hipStream_t stream)
{
    const int T = 128, B = 64, EMB = 400, HID = 1152, NTOK = 33278;
    const int TB = T * B;

    const float* x     = (const float*)d_in[0];
    const float* h0[3] = {(const float*)d_in[1], (const float*)d_in[2], (const float*)d_in[3]};
    const float* c0[3] = {(const float*)d_in[4], (const float*)d_in[5], (const float*)d_in[6]};
    const float* W_ih[3] = {(const float*)d_in[7],  (const float*)d_in[11], (const float*)d_in[15]};
    const float* W_hh[3] = {(const float*)d_in[8],  (const float*)d_in[12], (const float*)d_in[16]};
    const float* b_ih[3] = {(const float*)d_in[9],  (const float*)d_in[13], (const float*)d_in[17]};
    const float* b_hh[3] = {(const float*)d_in[10], (const float*)d_in[14], (const float*)d_in[18]};
    const float* W_dec = (const float*)d_in[19];
    const float* b_dec = (const float*)d_in[20];

    const int din[3]    = {EMB, HID, HID};     // input dim per layer
    const int Kpre[3]   = {416, 1152, 1152};   // padded K of pre-GEMM
    const int dh[3]     = {HID, HID, EMB};     // hidden dim per layer
    const int KpH[3]    = {1152, 1152, 576};   // padded h width (KT%6==0)
    const int N4[3]     = {4608, 4608, 1600};
    const int N4p128[3] = {4608, 4608, 1664};
    const int Gp[3]     = {144, 144, 50};      // persistent grid (N4/32)

    char* wsp = (char*)d_ws;
    size_t off = 0;
    auto alloc = [&](size_t bytes) -> char* {
        char* p = wsp + off; off = (off + bytes + 255) & ~(size_t)255; return p;
    };

    float* pre   = (float*)alloc((size_t)4096 * 4608 * 4);        // 75.5 MB (half T)
    u16* seqHi   = (u16*)alloc((size_t)TB * 1152 * 2);            // 18.9 MB
    u16* seqLo   = (u16*)alloc((size_t)TB * 1152 * 2);            // 18.9 MB
    u16* WihHi   = (u16*)alloc((size_t)4608 * 1152 * 2);          // 10.6 MB
    u16* WihLo   = (u16*)alloc((size_t)4608 * 1152 * 2);
    u16* WhhHi   = (u16*)alloc((size_t)4608 * 1152 * 2);
    u16* WhhLo   = (u16*)alloc((size_t)4608 * 1152 * 2);
    u16* h0Hi    = (u16*)alloc((size_t)B * 1152 * 2);
    u16* h0Lo    = (u16*)alloc((size_t)B * 1152 * 2);
    float* bsum  = (float*)alloc(4608 * 4);
    float* cstb  = (float*)alloc((size_t)B * HID * 4);
    // sync buffers: gcnt [6][64][8][32], rootc [6][64][32], go [6][64]
    const size_t gcntN = (size_t)6 * 64 * 8 * 32;
    const size_t rootN = (size_t)6 * 64 * 32;
    const size_t goN   = (size_t)6 * 64;
    int* syncbuf = (int*)alloc((gcntN + rootN + goN) * 4);
    int* gcnt  = syncbuf;
    int* rootc = syncbuf + gcntN;
    int* go    = syncbuf + gcntN + rootN;
    // decoder W split aliases pre (pre dead by then): 2 x 27.7 MB <= 75.5 MB
    u16* WdecHi  = (u16*)pre;
    u16* WdecLo  = (u16*)pre + (size_t)33280 * 416;

    hipMemsetAsync(syncbuf, 0, (gcntN + rootN + goN) * 4, stream);
    hipFuncSetAttribute(reinterpret_cast<const void*>(persistent_lstm),
                        hipFuncAttributeMaxDynamicSharedMemorySize, 160 * 1024);

    auto run_split = [&](const float* src, u16* hi, u16* lo,
                         int N, int K, int Npad, int Kpad, int perm) {
        int total = Npad * Kpad;
        split_pad_kernel<<<(total + 255) / 256, 256, 0, stream>>>(
            src, hi, lo, N, K, Npad, Kpad, perm);
    };

    for (int l = 0; l < 3; ++l) {
        run_split(W_hh[l], WhhHi, WhhLo, N4[l], dh[l], N4[l], KpH[l], 1);
        run_split(h0[l], h0Hi, h0Lo, B, dh[l], B, KpH[l], 0);
        run_split(W_ih[l], WihHi, WihLo, N4[l], din[l], N4p128[l], Kpre[l], 1);
        bias_perm_kernel<<<(N4[l] + 255) / 256, 256, 0, stream>>>(
            b_ih[l], b_hh[l], bsum, N4[l]);

        const int ldaA = (l == 0) ? EMB : KpH[l - 1];
        const size_t ldsB = (size_t)128 * KpH[l];   // 2*32*Kp*2 bytes

        for (int halfT = 0; halfT < 2; ++halfT) {
            const int li = l * 2 + halfT;
            const float* Af32 = (l == 0) ? (x + (size_t)halfT * 4096 * EMB) : nullptr;
            const u16* Ah = (l == 0) ? nullptr : (seqHi + (size_t)halfT * 4096 * ldaA);
            const u16* Al = (l == 0) ? nullptr : (seqLo + (size_t)halfT * 4096 * ldaA);
            gemm3m<<<dim3(N4p128[l] / 128, 32), 256, 0, stream>>>(
                Af32, Ah, Al, WihHi, WihLo, bsum, pre,
                N4[l], din[l], Kpre[l], ldaA, N4[l], (l == 0) ? 0 : 1);

            const float* cin = (halfT == 0) ? c0[l] : cstb;
            persistent_lstm<<<dim3(Gp[l]), 256, ldsB, stream>>>(
                WhhHi, WhhLo, h0Hi, h0Lo, seqHi, seqLo, pre,
                cin, cstb,
                gcnt + (size_t)li * 64 * 8 * 32,
                rootc + (size_t)li * 64 * 32,
                go + (size_t)li * 64,
                halfT * 64, N4[l], KpH[l], dh[l], Gp[l]);
        }
    }

    // decoder: out = H2 @ W_dec^T + b_dec   (A stride 576, K extent 416)
    run_split(W_dec, WdecHi, WdecLo, NTOK, EMB, 33280, 416, 0);
    gemm3m<<<dim3(260, 64), 256, 0, stream>>>(
        nullptr, seqHi, seqLo, WdecHi, WdecLo, b_dec, (float*)d_out,
        NTOK, EMB, 416, 576, NTOK, 1);
}

// Round 5
// 6535.744 us; speedup vs baseline: 6.3172x; 1.0325x over previous
//
#include <hip/hip_runtime.h>
#include <math.h>

typedef unsigned short u16;
typedef __attribute__((ext_vector_type(8))) short short8;
typedef __attribute__((ext_vector_type(4))) float f32x4;
typedef __attribute__((ext_vector_type(2))) float f32x2;

__device__ __forceinline__ u16 f32_to_bf16(float x) {
    union { float f; unsigned int u; } v; v.f = x;
    unsigned int u = v.u;
    return (u16)((u + 0x7FFFu + ((u >> 16) & 1u)) >> 16);
}
__device__ __forceinline__ float bf16_to_f32(u16 h) {
    union { unsigned int u; float f; } v; v.u = ((unsigned int)h) << 16; return v.f;
}

// ---------------------------------------------------------------------------
// split fp32 [N][K] (optionally gate-permuted rows) -> bf16 hi/lo [Npad][Kpad]
// perm=1: source row for dst row n is (n&3)*(N/4) + (n>>2)   (c = j*4+g)
// ---------------------------------------------------------------------------
__global__ void split_pad_kernel(const float* __restrict__ src,
                                 u16* __restrict__ hi, u16* __restrict__ lo,
                                 int N, int K, int Npad, int Kpad, int perm)
{
    int idx = blockIdx.x * 256 + threadIdx.x;
    if (idx >= Npad * Kpad) return;
    int n = idx / Kpad, k = idx - n * Kpad;
    float x = 0.f;
    if (n < N && k < K) {
        int srow = n;
        if (perm) { int dout = N >> 2; srow = (n & 3) * dout + (n >> 2); }
        x = src[(size_t)srow * K + k];
    }
    u16 h = f32_to_bf16(x);
    hi[idx] = h;
    lo[idx] = f32_to_bf16(x - bf16_to_f32(h));
}

__global__ void bias_perm_kernel(const float* __restrict__ bi,
                                 const float* __restrict__ bh,
                                 float* __restrict__ out, int N4)
{
    int c = blockIdx.x * 256 + threadIdx.x;
    if (c >= N4) return;
    int dout = N4 >> 2;
    int s = (c & 3) * dout + (c >> 2);
    out[c] = bi[s] + bh[s];
}

// ---------------------------------------------------------------------------
// C[M][ldc] = A @ W^T + bias, bf16x3 MFMA.
// 1-D grid NT*MT, supergrouped order: NSUB n-tiles x all MT m-tiles per group
// (W supertile stays L2-resident). Dynamic LDS 32KB: As/Ws for main loop,
// aliased by Cs[32][129] f32 for the coalesced epilogue.
// ---------------------------------------------------------------------------
__global__ __launch_bounds__(256) void gemm3m(
    const float* __restrict__ Af32,
    const u16* __restrict__ Ahi, const u16* __restrict__ Alo,
    const u16* __restrict__ Whi, const u16* __restrict__ Wlo,
    const float* __restrict__ bias,
    float* __restrict__ C,
    int Nreal, int Kreal, int Kp, int lda, int ldc, int amode,
    int MT, int NSUB)
{
    extern __shared__ __align__(16) char smem[];
    u16 (*As)[128][32] = (u16 (*)[128][32])smem;            // [2][128][32]
    u16 (*Ws)[128][32] = (u16 (*)[128][32])(smem + 16384);  // [2][128][32]
    float (*Cs)[129]   = (float (*)[129])smem;              // epilogue alias

    const int tid  = threadIdx.x;
    const int lane = tid & 63, wave = tid >> 6;

    // supergrouped block remap
    const int bid   = blockIdx.x;
    const int super = bid / (NSUB * MT);
    const int rem   = bid - super * (NSUB * MT);
    const int mtile = rem / NSUB;
    const int ntile = super * NSUB + (rem - mtile * NSUB);
    const int m0 = mtile * 128, n0 = ntile * 128;

    const int wm = (wave >> 1) * 64, wn = (wave & 1) * 64;

    f32x4 acc[4][4];
#pragma unroll
    for (int i = 0; i < 4; ++i)
#pragma unroll
        for (int j = 0; j < 4; ++j)
#pragma unroll
            for (int r = 0; r < 4; ++r) acc[i][j][r] = 0.f;

    const int srow = tid >> 2;
    const int sq   = tid & 3;
    const int dq   = (sq ^ ((srow >> 2) & 3)) * 8;
    const int fr   = lane & 15;
    const int fq   = lane >> 4;
    const int rcol = (fq ^ ((fr >> 2) & 3)) * 8;

    for (int k0 = 0; k0 < Kp; k0 += 32) {
#pragma unroll
        for (int half = 0; half < 2; ++half) {
            int row = half * 64 + srow;
            int kc  = k0 + sq * 8;
            if (amode == 0) {
                union { u16 s[8]; short8 v; } uh, ul;
                if (kc + 8 <= Kreal) {
                    const float* p = &Af32[(size_t)(m0 + row) * lda + kc];
#pragma unroll
                    for (int j = 0; j < 8; ++j) {
                        float xv = p[j];
                        u16 hh = f32_to_bf16(xv);
                        uh.s[j] = hh;
                        ul.s[j] = f32_to_bf16(xv - bf16_to_f32(hh));
                    }
                } else {
#pragma unroll
                    for (int j = 0; j < 8; ++j) { uh.s[j] = 0; ul.s[j] = 0; }
                }
                *(short8*)&As[0][row][dq] = uh.v;
                *(short8*)&As[1][row][dq] = ul.v;
            } else {
                size_t ao = (size_t)(m0 + row) * lda + kc;
                *(short8*)&As[0][row][dq] = *(const short8*)(Ahi + ao);
                *(short8*)&As[1][row][dq] = *(const short8*)(Alo + ao);
            }
            size_t wo = (size_t)(n0 + row) * Kp + kc;
            *(short8*)&Ws[0][row][dq] = *(const short8*)(Whi + wo);
            *(short8*)&Ws[1][row][dq] = *(const short8*)(Wlo + wo);
        }
        __syncthreads();

        short8 ah[4], al[4], wh[4], wl[4];
#pragma unroll
        for (int f = 0; f < 4; ++f) {
            int arow = wm + f * 16 + fr;
            ah[f] = *(const short8*)&As[0][arow][rcol];
            al[f] = *(const short8*)&As[1][arow][rcol];
            int wrow = wn + f * 16 + fr;
            wh[f] = *(const short8*)&Ws[0][wrow][rcol];
            wl[f] = *(const short8*)&Ws[1][wrow][rcol];
        }
#pragma unroll
        for (int i = 0; i < 4; ++i)
#pragma unroll
            for (int j = 0; j < 4; ++j) {
                acc[i][j] = __builtin_amdgcn_mfma_f32_16x16x32_bf16(ah[i], wh[j], acc[i][j], 0, 0, 0);
                acc[i][j] = __builtin_amdgcn_mfma_f32_16x16x32_bf16(ah[i], wl[j], acc[i][j], 0, 0, 0);
                acc[i][j] = __builtin_amdgcn_mfma_f32_16x16x32_bf16(al[i], wh[j], acc[i][j], 0, 0, 0);
            }
        __syncthreads();
    }

    // ---- coalesced epilogue via LDS bounce: per i, 32 rows x 128 cols ----
    const int erow = tid & 31;     // LDS row 0..31
    const int echk = tid >> 5;     // 16-col chunk 0..7
    const int gm_base = m0 + ((erow >> 4) * 64) + (erow & 15);
    const int gn0 = n0 + echk * 16;
    const bool vec4ok = ((ldc & 3) == 0);

#pragma unroll
    for (int i = 0; i < 4; ++i) {
        __syncthreads();
#pragma unroll
        for (int j = 0; j < 4; ++j)
#pragma unroll
            for (int r = 0; r < 4; ++r)
                Cs[(wave >> 1) * 16 + fq * 4 + r][wn + j * 16 + fr] = acc[i][j][r];
        __syncthreads();

        const int gm = gm_base + i * 16;
        float* crow = C + (size_t)gm * ldc;
        if (gn0 + 16 <= Nreal) {
#pragma unroll
            for (int q = 0; q < 4; ++q) {
                f32x4 v = *(const f32x4*)&Cs[erow][echk * 16 + q * 4];
                if (bias) {
                    f32x4 bv = *(const f32x4*)&bias[gn0 + q * 4];
                    v += bv;
                }
                if (vec4ok) {
                    *(f32x4*)&crow[gn0 + q * 4] = v;
                } else {
                    f32x2 lo2 = {v[0], v[1]}, hi2 = {v[2], v[3]};
                    *(f32x2*)&crow[gn0 + q * 4]     = lo2;
                    *(f32x2*)&crow[gn0 + q * 4 + 2] = hi2;
                }
            }
        } else {
#pragma unroll
            for (int q = 0; q < 4; ++q)
#pragma unroll
                for (int p = 0; p < 4; ++p) {
                    int n = gn0 + q * 4 + p;
                    if (n < Nreal)
                        crow[n] = Cs[erow][echk * 16 + q * 4 + p] + (bias ? bias[n] : 0.f);
                }
        }
    }
}

// ---------------------------------------------------------------------------
// Persistent LSTM, 64 timesteps per launch. W slice (32 gate-cols, hi+lo) in
// LDS. Depth-6 pipelined k-loop (KT % 6 == 0). Barrier: 8 padded group
// counters (blockIdx&7); arrival = release-wbl2 + group RMW; wait = poll
// sum of 8 counters (no root, no go flag, no acquire-invalidate -- h lines
// for step t are address-cold in every consumer's L2, release guarantees L3
// freshness). Next-step pre prefetched into regs before polling.
// ---------------------------------------------------------------------------
#define PF(S, KT_) do {                                                        \
    int q_ = (((KT_) * 4 + fq) ^ sxor) * 8;                                    \
    a0h_##S = *(const short8*)&Wlds[rA * Kp + q_];                             \
    a0l_##S = *(const short8*)&Wlds[(32 + rA) * Kp + q_];                      \
    a1h_##S = *(const short8*)&Wlds[rB * Kp + q_];                             \
    a1l_##S = *(const short8*)&Wlds[(32 + rB) * Kp + q_];                      \
    hh_##S = *(const short8*)(hrow_hi + (KT_) * 32 + fq * 8);                  \
    hl_##S = *(const short8*)(hrow_lo + (KT_) * 32 + fq * 8);                  \
} while (0)

#define CM(S) do {                                                             \
    accA = __builtin_amdgcn_mfma_f32_16x16x32_bf16(a0h_##S, hh_##S, accA, 0, 0, 0); \
    accB = __builtin_amdgcn_mfma_f32_16x16x32_bf16(a1h_##S, hh_##S, accB, 0, 0, 0); \
    accA = __builtin_amdgcn_mfma_f32_16x16x32_bf16(a0h_##S, hl_##S, accA, 0, 0, 0); \
    accB = __builtin_amdgcn_mfma_f32_16x16x32_bf16(a1h_##S, hl_##S, accB, 0, 0, 0); \
    accA = __builtin_amdgcn_mfma_f32_16x16x32_bf16(a0l_##S, hh_##S, accA, 0, 0, 0); \
    accB = __builtin_amdgcn_mfma_f32_16x16x32_bf16(a1l_##S, hh_##S, accB, 0, 0, 0); \
} while (0)

__global__ __launch_bounds__(256, 1) void persistent_lstm(
    const u16* __restrict__ Whi, const u16* __restrict__ Wlo,   // [N4][Kp]
    const u16* __restrict__ h0hi, const u16* __restrict__ h0lo, // [64][Kp]
    u16* __restrict__ seqHi, u16* __restrict__ seqLo,           // [T*64][Kp]
    const float* __restrict__ pre,                              // [64*64][N4]
    const float* __restrict__ c_in, float* __restrict__ c_out,  // [64][dout]
    int* __restrict__ gcnt,   // [64][8] stride-32 padded group counters
    int t0, int N4, int Kp, int dout, int G)
{
    extern __shared__ __align__(16) u16 Wlds[];   // [2][32][Kp] swizzled
    const int tid  = threadIdx.x;
    const int lane = tid & 63, wave = tid >> 6;
    const int fr = lane & 15, fq = lane >> 4;
    const int c0blk = blockIdx.x * 32;
    const int CH = Kp >> 3;
    const int b = wave * 16 + fr;
    const int grp = blockIdx.x & 7;

    // stage W slice into LDS, chunk slot = q ^ (row&7)
    for (int idx = tid; idx < 64 * CH; idx += 256) {
        int buf = idx / (32 * CH);
        int rem = idx - buf * 32 * CH;
        int r = rem / CH, q = rem - r * CH;
        const u16* src = buf ? Wlo : Whi;
        short8 v = *(const short8*)(src + (size_t)(c0blk + r) * Kp + q * 8);
        *(short8*)&Wlds[(buf * 32 + r) * Kp + (q ^ (r & 7)) * 8] = v;
    }

    const int cA = c0blk + fq * 4;
    const int cB = cA + 16;
    const int jA = cA >> 2, jB = cB >> 2;
    float cregA = c_in[(size_t)b * dout + jA];
    float cregB = c_in[(size_t)b * dout + jB];

    const int rA = fr, rB = 16 + fr;
    const int sxor = fr & 7;
    const int KT = Kp >> 5;            // multiple of 6 by construction

    // pre for step 0
    f32x4 preA = *(const f32x4*)(pre + (size_t)b * N4 + cA);
    f32x4 preB = *(const f32x4*)(pre + (size_t)b * N4 + cB);
    __syncthreads();

    for (int ts = 0; ts < 64; ++ts) {
        const int t = t0 + ts;
        const u16* hbase_hi = (t == 0) ? h0hi : seqHi + (size_t)(t - 1) * 64 * Kp;
        const u16* hbase_lo = (t == 0) ? h0lo : seqLo + (size_t)(t - 1) * 64 * Kp;
        const u16* hrow_hi = hbase_hi + (size_t)b * Kp;
        const u16* hrow_lo = hbase_lo + (size_t)b * Kp;

        f32x4 accA = {0.f, 0.f, 0.f, 0.f};
        f32x4 accB = {0.f, 0.f, 0.f, 0.f};
        short8 a0h_0, a0l_0, a1h_0, a1l_0, hh_0, hl_0;
        short8 a0h_1, a0l_1, a1h_1, a1l_1, hh_1, hl_1;
        short8 a0h_2, a0l_2, a1h_2, a1l_2, hh_2, hl_2;
        short8 a0h_3, a0l_3, a1h_3, a1l_3, hh_3, hl_3;
        short8 a0h_4, a0l_4, a1h_4, a1l_4, hh_4, hl_4;
        short8 a0h_5, a0l_5, a1h_5, a1l_5, hh_5, hl_5;

        PF(0, 0); PF(1, 1); PF(2, 2); PF(3, 3); PF(4, 4); PF(5, 5);
        for (int kt = 0; kt < KT - 6; kt += 6) {
            CM(0); PF(0, kt + 6);
            CM(1); PF(1, kt + 7);
            CM(2); PF(2, kt + 8);
            CM(3); PF(3, kt + 9);
            CM(4); PF(4, kt + 10);
            CM(5); PF(5, kt + 11);
        }
        CM(0); CM(1); CM(2); CM(3); CM(4); CM(5);

        // epilogue: gates -> c,h ; write h (hi/lo)
#pragma unroll
        for (int ct = 0; ct < 2; ++ct) {
            f32x4 a = ct ? accB : accA;
            f32x4 p = ct ? preB : preA;
            int j  = ct ? jB : jA;
            float gi = a[0] + p[0];
            float gf = a[1] + p[1];
            float gg = a[2] + p[2];
            float go_ = a[3] + p[3];
            float si = 1.f / (1.f + expf(-gi));
            float sf = 1.f / (1.f + expf(-gf));
            float so = 1.f / (1.f + expf(-go_));
            float tg = tanhf(gg);
            float cn = sf * (ct ? cregB : cregA) + si * tg;
            float hv = so * tanhf(cn);
            if (ct) cregB = cn; else cregA = cn;
            u16 hb = f32_to_bf16(hv);
            size_t so_ = (size_t)(t * 64 + b) * Kp + j;
            seqHi[so_] = hb;
            seqLo[so_] = f32_to_bf16(hv - bf16_to_f32(hb));
        }

        if (ts != 63) {
            __syncthreads();   // drain all waves' h stores to L2
            // prefetch next-step pre while the barrier settles
            {
                const float* prow2 = pre + (size_t)((ts + 1) * 64 + b) * N4;
                preA = *(const f32x4*)(prow2 + cA);
                preB = *(const f32x4*)(prow2 + cB);
            }
            if (tid == 0) {
                __builtin_amdgcn_fence(__ATOMIC_RELEASE, "agent");   // wbl2
                __hip_atomic_fetch_add(&gcnt[(ts * 8 + grp) * 32], 1,
                                       __ATOMIC_RELAXED, __HIP_MEMORY_SCOPE_AGENT);
                int sum;
                do {
                    sum = 0;
#pragma unroll
                    for (int g = 0; g < 8; ++g)
                        sum += __hip_atomic_load(&gcnt[(ts * 8 + g) * 32],
                                                 __ATOMIC_RELAXED, __HIP_MEMORY_SCOPE_AGENT);
                    if (sum < G) __builtin_amdgcn_s_sleep(1);
                } while (sum < G);
            }
            __syncthreads();
            __builtin_amdgcn_sched_barrier(0);
        }
    }

    c_out[(size_t)b * dout + jA] = cregA;
    c_out[(size_t)b * dout + jB] = cregB;
}

// ---------------------------------------------------------------------------
extern "C" void kernel_launch(void* const* d_in, const int* in_sizes, int n_in,
                              void* d_out, int out_size, void* d_ws, size_t ws_size,
                              hipStream_t stream)
{
    const int T = 128, B = 64, EMB = 400, HID = 1152, NTOK = 33278;
    const int TB = T * B;

    const float* x     = (const float*)d_in[0];
    const float* h0[3] = {(const float*)d_in[1], (const float*)d_in[2], (const float*)d_in[3]};
    const float* c0[3] = {(const float*)d_in[4], (const float*)d_in[5], (const float*)d_in[6]};
    const float* W_ih[3] = {(const float*)d_in[7],  (const float*)d_in[11], (const float*)d_in[15]};
    const float* W_hh[3] = {(const float*)d_in[8],  (const float*)d_in[12], (const float*)d_in[16]};
    const float* b_ih[3] = {(const float*)d_in[9],  (const float*)d_in[13], (const float*)d_in[17]};
    const float* b_hh[3] = {(const float*)d_in[10], (const float*)d_in[14], (const float*)d_in[18]};
    const float* W_dec = (const float*)d_in[19];
    const float* b_dec = (const float*)d_in[20];

    const int din[3]    = {EMB, HID, HID};     // input dim per layer
    const int Kpre[3]   = {416, 1152, 1152};   // padded K of pre-GEMM
    const int dh[3]     = {HID, HID, EMB};     // hidden dim per layer
    const int KpH[3]    = {1152, 1152, 576};   // padded h width (KT%6==0)
    const int N4[3]     = {4608, 4608, 1600};
    const int N4p128[3] = {4608, 4608, 1664};
    const int NSUBpre[3] = {6, 6, 13};         // supergroup n-tiles
    const int Gp[3]     = {144, 144, 50};      // persistent grid (N4/32)

    char* wsp = (char*)d_ws;
    size_t off = 0;
    auto alloc = [&](size_t bytes) -> char* {
        char* p = wsp + off; off = (off + bytes + 255) & ~(size_t)255; return p;
    };

    float* pre   = (float*)alloc((size_t)4096 * 4608 * 4);        // 75.5 MB (half T)
    u16* seqHi   = (u16*)alloc((size_t)TB * 1152 * 2);            // 18.9 MB
    u16* seqLo   = (u16*)alloc((size_t)TB * 1152 * 2);            // 18.9 MB
    u16* WihHi   = (u16*)alloc((size_t)4608 * 1152 * 2);          // 10.6 MB
    u16* WihLo   = (u16*)alloc((size_t)4608 * 1152 * 2);
    u16* WhhHi   = (u16*)alloc((size_t)4608 * 1152 * 2);
    u16* WhhLo   = (u16*)alloc((size_t)4608 * 1152 * 2);
    u16* h0Hi    = (u16*)alloc((size_t)B * 1152 * 2);
    u16* h0Lo    = (u16*)alloc((size_t)B * 1152 * 2);
    float* bsum  = (float*)alloc(4608 * 4);
    float* cstb  = (float*)alloc((size_t)B * HID * 4);
    // sync buffers: gcnt [6 launches][64 steps][8 groups][32-int pad]
    const size_t gcntN = (size_t)6 * 64 * 8 * 32;
    int* gcnt = (int*)alloc(gcntN * 4);
    // decoder W split aliases pre (pre dead by then): 2 x 27.7 MB <= 75.5 MB
    u16* WdecHi  = (u16*)pre;
    u16* WdecLo  = (u16*)pre + (size_t)33280 * 416;

    hipMemsetAsync(gcnt, 0, gcntN * 4, stream);
    hipFuncSetAttribute(reinterpret_cast<const void*>(persistent_lstm),
                        hipFuncAttributeMaxDynamicSharedMemorySize, 160 * 1024);
    hipFuncSetAttribute(reinterpret_cast<const void*>(gemm3m),
                        hipFuncAttributeMaxDynamicSharedMemorySize, 64 * 1024);

    auto run_split = [&](const float* src, u16* hi, u16* lo,
                         int N, int K, int Npad, int Kpad, int perm) {
        int total = Npad * Kpad;
        split_pad_kernel<<<(total + 255) / 256, 256, 0, stream>>>(
            src, hi, lo, N, K, Npad, Kpad, perm);
    };

    for (int l = 0; l < 3; ++l) {
        run_split(W_hh[l], WhhHi, WhhLo, N4[l], dh[l], N4[l], KpH[l], 1);
        run_split(h0[l], h0Hi, h0Lo, B, dh[l], B, KpH[l], 0);
        run_split(W_ih[l], WihHi, WihLo, N4[l], din[l], N4p128[l], Kpre[l], 1);
        bias_perm_kernel<<<(N4[l] + 255) / 256, 256, 0, stream>>>(
            b_ih[l], b_hh[l], bsum, N4[l]);

        const int ldaA = (l == 0) ? EMB : KpH[l - 1];
        const int NT = N4p128[l] / 128, MT = 32;
        const size_t ldsB = (size_t)128 * KpH[l];   // 2*32*Kp*2 bytes

        for (int halfT = 0; halfT < 2; ++halfT) {
            const int li = l * 2 + halfT;
            const float* Af32 = (l == 0) ? (x + (size_t)halfT * 4096 * EMB) : nullptr;
            const u16* Ah = (l == 0) ? nullptr : (seqHi + (size_t)halfT * 4096 * ldaA);
            const u16* Al = (l == 0) ? nullptr : (seqLo + (size_t)halfT * 4096 * ldaA);
            gemm3m<<<dim3(NT * MT), 256, 32768, stream>>>(
                Af32, Ah, Al, WihHi, WihLo, bsum, pre,
                N4[l], din[l], Kpre[l], ldaA, N4[l], (l == 0) ? 0 : 1,
                MT, NSUBpre[l]);

            const float* cin = (halfT == 0) ? c0[l] : cstb;
            persistent_lstm<<<dim3(Gp[l]), 256, ldsB, stream>>>(
                WhhHi, WhhLo, h0Hi, h0Lo, seqHi, seqLo, pre,
                cin, cstb,
                gcnt + (size_t)li * 64 * 8 * 32,
                halfT * 64, N4[l], KpH[l], dh[l], Gp[l]);
        }
    }

    // decoder: out = H2 @ W_dec^T + b_dec   (A stride 576, K extent 416)
    run_split(W_dec, WdecHi, WdecLo, NTOK, EMB, 33280, 416, 0);
    gemm3m<<<dim3(260 * 64), 256, 32768, stream>>>(
        nullptr, seqHi, seqLo, WdecHi, WdecLo, b_dec, (float*)d_out,
        NTOK, EMB, 416, 576, NTOK, 1,
        64, 5);
}